// Round 4
// baseline (361.189 us; speedup 1.0000x reference)
//
#include <hip/hip_runtime.h>
#include <hip/hip_bf16.h>

#define N_NODES 50000
#define N_EDGES 800000
#define DIM 128
#define NTILES (N_EDGES / 64)   // 12500 exactly
#define SCAN_B 196              // ceil(50000/256)

typedef __bf16 bf16x8 __attribute__((ext_vector_type(8)));
typedef float f32x4 __attribute__((ext_vector_type(4)));
typedef unsigned int u32x4 __attribute__((ext_vector_type(4)));

__device__ __forceinline__ unsigned short f2bf(float f) {
    unsigned u = __float_as_uint(f);
    u += 0x7fffu + ((u >> 16) & 1u);          // round-to-nearest-even
    return (unsigned short)(u >> 16);
}

// ---- weights: W1t=bf16(W1)^T, Wat=bf16(W2a-W2b)^T, Wbt=bf16(W2b)^T, W3t=bf16(W3)^T
// identity: [h_i, h_j-h_i] @ W2 = h_i @ (W2a - W2b) + h_j @ W2b
__global__ void convert_w_kernel(const float* __restrict__ W1, const float* __restrict__ W2,
                                 const float* __restrict__ W3,
                                 unsigned short* __restrict__ W1t, unsigned short* __restrict__ Wat,
                                 unsigned short* __restrict__ Wbt, unsigned short* __restrict__ W3t) {
    int i = blockIdx.x * 256 + threadIdx.x;   // grid covers exactly 4*16384 = 65536
    int j = i & (DIM * DIM - 1);
    int k = j >> 7, n = j & 127;
    int sec = i >> 14;
    if (sec == 0)      W1t[n * 128 + k] = f2bf(W1[k * 128 + n]);
    else if (sec == 1) Wat[n * 128 + k] = f2bf(W2[k * 128 + n] - W2[(k + 128) * 128 + n]);
    else if (sec == 2) Wbt[n * 128 + k] = f2bf(W2[(k + 128) * 128 + n]);
    else               W3t[n * 128 + k] = f2bf(W3[k * 128 + n]);
}

// ---- counting sort by dst: histogram
__global__ void hist_kernel(const int* __restrict__ eidx, int* __restrict__ cnt) {
    int e = blockIdx.x * 256 + threadIdx.x;
    if (e < N_EDGES) atomicAdd(&cnt[eidx[N_EDGES + e]], 1);
}

// ---- hierarchical exclusive scan: A (per-block local scan + totals) -> B (scan totals)
__global__ void scanA_kernel(int* __restrict__ cnt, int* __restrict__ aux) {
    __shared__ int buf[256];
    int t = threadIdx.x, i = blockIdx.x * 256 + t;
    int v = (i < N_NODES) ? cnt[i] : 0;
    buf[t] = v;
    __syncthreads();
    for (int off = 1; off < 256; off <<= 1) {
        int u = (t >= off) ? buf[t - off] : 0;
        __syncthreads();
        buf[t] += u;
        __syncthreads();
    }
    if (i < N_NODES) cnt[i] = buf[t] - v;         // exclusive within block
    if (t == 255) aux[blockIdx.x] = buf[255];     // block total
}

__global__ void scanB_kernel(int* __restrict__ aux) {
    __shared__ int buf[256];
    int t = threadIdx.x;
    int v = (t < SCAN_B) ? aux[t] : 0;
    buf[t] = v;
    __syncthreads();
    for (int off = 1; off < 256; off <<= 1) {
        int u = (t >= off) ? buf[t - off] : 0;
        __syncthreads();
        buf[t] += u;
        __syncthreads();
    }
    if (t < SCAN_B) aux[t] = buf[t] - v;          // exclusive block offsets
}

// ---- scatter edges into dst-sorted order (scanC fused: global pos = local atomic + aux[block])
__global__ void scatter_kernel(const int* __restrict__ eidx, int* __restrict__ cursor,
                               const int* __restrict__ aux, int2* __restrict__ spair) {
    int e = blockIdx.x * 256 + threadIdx.x;
    if (e < N_EDGES) {
        int d = eidx[N_EDGES + e];
        int p = atomicAdd(&cursor[d], 1) + aux[d >> 8];
        spair[p] = make_int2(eidx[e], d);
    }
}

// ---- lin1: hbf[N][128] = bf16(x @ W1 + b1); bf16 W1t staged via 16B vector loads
__global__ __launch_bounds__(256, 2) void lin1_kernel(const float* __restrict__ x,
        const unsigned short* __restrict__ W1t, const float* __restrict__ b1,
        unsigned short* __restrict__ hbf) {
    __shared__ __align__(16) unsigned short w1t[128 * 136];
    int tid = threadIdx.x;
    #pragma unroll
    for (int it = 0; it < 8; it++) {
        int idx = (tid + it * 256) * 8;           // element offset, 8 shorts / 16B
        int n = idx >> 7, k = idx & 127;
        *(u32x4*)(&w1t[n * 136 + k]) = *(const u32x4*)(&W1t[idx]);
    }
    __syncthreads();
    int w = tid >> 6, lane = tid & 63;
    int lr = lane & 15, q = lane >> 4;
    int row0 = blockIdx.x * 64 + w * 16;
    int rowA = row0 + lr; if (rowA >= N_NODES) rowA = N_NODES - 1;
    f32x4 acc[8];
    #pragma unroll
    for (int ct = 0; ct < 8; ct++) acc[ct] = (f32x4){0.f, 0.f, 0.f, 0.f};
    #pragma unroll
    for (int kt = 0; kt < 4; kt++) {
        const float* ap = x + (size_t)rowA * DIM + kt * 32 + q * 8;
        f32x4 x0 = *(const f32x4*)(ap);
        f32x4 x1 = *(const f32x4*)(ap + 4);
        bf16x8 a;
        #pragma unroll
        for (int j = 0; j < 4; j++) { a[j] = (__bf16)x0[j]; a[j + 4] = (__bf16)x1[j]; }
        #pragma unroll
        for (int ct = 0; ct < 8; ct++) {
            bf16x8 b = __builtin_bit_cast(bf16x8,
                *(const u32x4*)(&w1t[(ct * 16 + lr) * 136 + kt * 32 + q * 8]));
            acc[ct] = __builtin_amdgcn_mfma_f32_16x16x32_bf16(a, b, acc[ct], 0, 0, 0);
        }
    }
    #pragma unroll
    for (int ct = 0; ct < 8; ct++) {
        int col = ct * 16 + lr;
        float bias = b1[col];
        #pragma unroll
        for (int r = 0; r < 4; r++) {
            int row = row0 + q * 4 + r;   // C/D: col=lane&15, row=quad*4+reg
            if (row < N_NODES)
                hbf[(size_t)row * DIM + col] = f2bf(acc[ct][r] + bias);
        }
    }
}

// ---- fused edge MLP + segmented scatter-max, software-pipelined gather
__global__ __launch_bounds__(256, 2) void edge_kernel(
        const unsigned short* __restrict__ hbf,
        const int2* __restrict__ spair,
        const unsigned short* __restrict__ Wat,
        const unsigned short* __restrict__ Wbt,
        const unsigned short* __restrict__ W3t,
        const float* __restrict__ b2,
        const float* __restrict__ b3,
        unsigned int* __restrict__ out) {
    __shared__ __align__(16) unsigned short gbuf[2 * 64 * 136];  // hi|hj; reused as fp32 m2 [64][132]
    __shared__ __align__(16) unsigned short m1_lds[64 * 136];
    __shared__ int s_dst[64];

    unsigned short* hi_lds = gbuf;
    unsigned short* hj_lds = gbuf + 64 * 136;
    float* m2f = (float*)gbuf;

    int tid = threadIdx.x;
    int w = tid >> 6, lane = tid & 63;
    int lr = lane & 15, q = lane >> 4;
    int tr = tid >> 4;             // tile-row group 0..15
    int c = (tid & 15) * 8;        // col chunk (shorts)

    // register-cached B fragments (fixed cols per wave, amortized over grid-stride loop)
    bf16x8 baf[2][4], bbf[2][4], b3f[2][4];
    float b2v[2], b3v[2];
    #pragma unroll
    for (int ct = 0; ct < 2; ct++) {
        int n = (2 * w + ct) * 16 + lr;
        #pragma unroll
        for (int kt = 0; kt < 4; kt++) {
            baf[ct][kt] = __builtin_bit_cast(bf16x8, *(const u32x4*)(&Wat[n * 128 + kt * 32 + q * 8]));
            bbf[ct][kt] = __builtin_bit_cast(bf16x8, *(const u32x4*)(&Wbt[n * 128 + kt * 32 + q * 8]));
            b3f[ct][kt] = __builtin_bit_cast(bf16x8, *(const u32x4*)(&W3t[n * 128 + kt * 32 + q * 8]));
        }
        b2v[ct] = b2[n];
        b3v[ct] = b3[n];
    }

    // prologue prefetch: tile blockIdx.x
    int tb = blockIdx.x;
    int2 pr[4];
    u32x4 gi[4], gj[4];
    {
        int eb = tb * 64;
        #pragma unroll
        for (int it = 0; it < 4; it++) pr[it] = spair[eb + tr + 16 * it];
        #pragma unroll
        for (int it = 0; it < 4; it++) {
            gi[it] = *(const u32x4*)(&hbf[(size_t)pr[it].y * DIM + c]);
            gj[it] = *(const u32x4*)(&hbf[(size_t)pr[it].x * DIM + c]);
        }
    }

    for (; tb < NTILES; tb += gridDim.x) {
        // commit staged gather to LDS
        #pragma unroll
        for (int it = 0; it < 4; it++) {
            int t = tr + 16 * it;
            *(u32x4*)(&hi_lds[t * 136 + c]) = gi[it];
            *(u32x4*)(&hj_lds[t * 136 + c]) = gj[it];
        }
        if ((tid & 15) == 0) {
            #pragma unroll
            for (int it = 0; it < 4; it++) s_dst[tr + 16 * it] = pr[it].y;
        }
        __syncthreads();

        // issue next tile's prefetch (indices then gathers) — retires under GEMMs/segmax
        int nx = tb + (int)gridDim.x;
        if (nx < NTILES) {
            int eb = nx * 64;
            #pragma unroll
            for (int it = 0; it < 4; it++) pr[it] = spair[eb + tr + 16 * it];
            #pragma unroll
            for (int it = 0; it < 4; it++) {
                gi[it] = *(const u32x4*)(&hbf[(size_t)pr[it].y * DIM + c]);
                gj[it] = *(const u32x4*)(&hbf[(size_t)pr[it].x * DIM + c]);
            }
        }

        // GEMM1: m1 = relu(h_i@Wa + h_j@Wb + b2)
        f32x4 acc1[4][2];
        #pragma unroll
        for (int rt = 0; rt < 4; rt++)
            #pragma unroll
            for (int ct = 0; ct < 2; ct++) acc1[rt][ct] = (f32x4){0.f, 0.f, 0.f, 0.f};
        #pragma unroll
        for (int kt = 0; kt < 4; kt++) {
            #pragma unroll
            for (int rt = 0; rt < 4; rt++) {
                bf16x8 ai = __builtin_bit_cast(bf16x8,
                    *(const u32x4*)(&hi_lds[(rt * 16 + lr) * 136 + kt * 32 + q * 8]));
                bf16x8 aj = __builtin_bit_cast(bf16x8,
                    *(const u32x4*)(&hj_lds[(rt * 16 + lr) * 136 + kt * 32 + q * 8]));
                acc1[rt][0] = __builtin_amdgcn_mfma_f32_16x16x32_bf16(ai, baf[0][kt], acc1[rt][0], 0, 0, 0);
                acc1[rt][1] = __builtin_amdgcn_mfma_f32_16x16x32_bf16(ai, baf[1][kt], acc1[rt][1], 0, 0, 0);
                acc1[rt][0] = __builtin_amdgcn_mfma_f32_16x16x32_bf16(aj, bbf[0][kt], acc1[rt][0], 0, 0, 0);
                acc1[rt][1] = __builtin_amdgcn_mfma_f32_16x16x32_bf16(aj, bbf[1][kt], acc1[rt][1], 0, 0, 0);
            }
        }
        #pragma unroll
        for (int rt = 0; rt < 4; rt++) {
            #pragma unroll
            for (int ct = 0; ct < 2; ct++) {
                int col = (2 * w + ct) * 16 + lr;
                #pragma unroll
                for (int r = 0; r < 4; r++) {
                    float v = fmaxf(acc1[rt][ct][r] + b2v[ct], 0.f);
                    m1_lds[(rt * 16 + q * 4 + r) * 136 + col] = f2bf(v);
                }
            }
        }
        __syncthreads();   // m1 ready; GEMM1 reads of gbuf done -> m2f reuse safe

        // GEMM2: m2 = relu(m1 @ W3 + b3)
        f32x4 acc2[4][2];
        #pragma unroll
        for (int rt = 0; rt < 4; rt++)
            #pragma unroll
            for (int ct = 0; ct < 2; ct++) acc2[rt][ct] = (f32x4){0.f, 0.f, 0.f, 0.f};
        #pragma unroll
        for (int kt = 0; kt < 4; kt++) {
            #pragma unroll
            for (int rt = 0; rt < 4; rt++) {
                bf16x8 a = __builtin_bit_cast(bf16x8,
                    *(const u32x4*)(&m1_lds[(rt * 16 + lr) * 136 + kt * 32 + q * 8]));
                acc2[rt][0] = __builtin_amdgcn_mfma_f32_16x16x32_bf16(a, b3f[0][kt], acc2[rt][0], 0, 0, 0);
                acc2[rt][1] = __builtin_amdgcn_mfma_f32_16x16x32_bf16(a, b3f[1][kt], acc2[rt][1], 0, 0, 0);
            }
        }
        #pragma unroll
        for (int rt = 0; rt < 4; rt++) {
            #pragma unroll
            for (int ct = 0; ct < 2; ct++) {
                int col = (2 * w + ct) * 16 + lr;
                #pragma unroll
                for (int r = 0; r < 4; r++) {
                    float v = fmaxf(acc2[rt][ct][r] + b3v[ct], 0.f);
                    m2f[(rt * 16 + q * 4 + r) * 132 + col] = v;
                }
            }
        }
        __syncthreads();

        // segmented max over sorted dst runs: thread -> (col = tid&127, rows r0..r0+31)
        {
            int col = tid & 127;
            int r0 = (tid >> 7) * 32;
            float cur = m2f[r0 * 132 + col];
            int d = s_dst[r0];                          // wave-uniform
            #pragma unroll 4
            for (int i = 1; i < 32; i++) {
                int dn = s_dst[r0 + i];                 // wave-uniform
                float v = m2f[(r0 + i) * 132 + col];
                if (dn != d) {                          // wave-uniform branch
                    atomicMax(&out[(size_t)d * DIM + col], __float_as_uint(cur));
                    d = dn; cur = v;
                } else {
                    cur = fmaxf(cur, v);
                }
            }
            atomicMax(&out[(size_t)d * DIM + col], __float_as_uint(cur));
        }
        __syncthreads();   // protect s_dst/gbuf/m1_lds before next tile's commit
    }
}

extern "C" void kernel_launch(void* const* d_in, const int* in_sizes, int n_in,
                              void* d_out, int out_size, void* d_ws, size_t ws_size,
                              hipStream_t stream) {
    const float* x  = (const float*)d_in[0];
    const int* eidx = (const int*)d_in[1];
    const float* W1 = (const float*)d_in[2];
    const float* b1 = (const float*)d_in[3];
    const float* W2 = (const float*)d_in[4];
    const float* b2 = (const float*)d_in[5];
    const float* W3 = (const float*)d_in[6];
    const float* b3 = (const float*)d_in[7];

    char* ws = (char*)d_ws;
    unsigned short* hbf = (unsigned short*)ws;                     // 12,800,000 B
    unsigned short* W1t = (unsigned short*)(ws + 12800000);        // 32,768 B
    unsigned short* Wat = (unsigned short*)(ws + 12832768);        // 32,768 B
    unsigned short* Wbt = (unsigned short*)(ws + 12865536);        // 32,768 B
    unsigned short* W3t = (unsigned short*)(ws + 12898304);        // 32,768 B
    int* cnt            = (int*)(ws + 12931072);                   // 200,000 B
    int2* spair         = (int2*)(ws + 13131072);                  // 6,400,000 B -> 19,531,072 total
    int* aux            = (int*)hbf;   // aliases hbf head: dead before lin1 (ordered after scatter)

    hipMemsetAsync(d_out, 0, (size_t)N_NODES * DIM * sizeof(float), stream);
    hipMemsetAsync(cnt, 0, N_NODES * sizeof(int), stream);
    convert_w_kernel<<<256, 256, 0, stream>>>(W1, W2, W3, W1t, Wat, Wbt, W3t);
    hist_kernel<<<(N_EDGES + 255) / 256, 256, 0, stream>>>(eidx, cnt);
    scanA_kernel<<<SCAN_B, 256, 0, stream>>>(cnt, aux);
    scanB_kernel<<<1, 256, 0, stream>>>(aux);
    scatter_kernel<<<(N_EDGES + 255) / 256, 256, 0, stream>>>(eidx, cnt, aux, spair);
    lin1_kernel<<<(N_NODES + 63) / 64, 256, 0, stream>>>(x, W1t, b1, hbf);   // after scatter: overwrites aux
    edge_kernel<<<2048, 256, 0, stream>>>(hbf, spair, Wat, Wbt, W3t, b2, b3, (unsigned int*)d_out);
}

// Round 5
// 340.993 us; speedup vs baseline: 1.0592x; 1.0592x over previous
//
#include <hip/hip_runtime.h>
#include <hip/hip_bf16.h>

#define N_NODES 50000
#define N_EDGES 800000
#define DIM 128
#define NTILES (N_EDGES / 64)   // 12500 exactly
#define SCAN_B 196              // ceil(50000/256)
#define HIST_B 3125             // 800000/256
#define LIN1_B 782              // ceil(50000/64)

typedef __bf16 bf16x8 __attribute__((ext_vector_type(8)));
typedef float f32x4 __attribute__((ext_vector_type(4)));
typedef unsigned int u32x4 __attribute__((ext_vector_type(4)));

__device__ __forceinline__ unsigned short f2bf(float f) {
    unsigned u = __float_as_uint(f);
    u += 0x7fffu + ((u >> 16) & 1u);          // round-to-nearest-even
    return (unsigned short)(u >> 16);
}

// ---- K1: weight convert (blocks 0..255) + dst histogram (blocks 256..3380)
// identity: [h_i, h_j-h_i] @ W2 = h_i @ (W2a - W2b) + h_j @ W2b
__global__ void prep_kernel(const float* __restrict__ W1, const float* __restrict__ W2,
                            const float* __restrict__ W3, const int* __restrict__ eidx,
                            unsigned short* __restrict__ W1t, unsigned short* __restrict__ Wat,
                            unsigned short* __restrict__ Wbt, unsigned short* __restrict__ W3t,
                            int* __restrict__ cnt) {
    int bid = blockIdx.x;
    if (bid < 256) {
        int i = bid * 256 + threadIdx.x;      // 0..65535
        int j = i & (DIM * DIM - 1);
        int k = j >> 7, n = j & 127;
        int sec = i >> 14;
        if (sec == 0)      W1t[n * 128 + k] = f2bf(W1[k * 128 + n]);
        else if (sec == 1) Wat[n * 128 + k] = f2bf(W2[k * 128 + n] - W2[(k + 128) * 128 + n]);
        else if (sec == 2) Wbt[n * 128 + k] = f2bf(W2[(k + 128) * 128 + n]);
        else               W3t[n * 128 + k] = f2bf(W3[k * 128 + n]);
    } else {
        int e = (bid - 256) * 256 + threadIdx.x;   // exactly covers 800000
        atomicAdd(&cnt[eidx[N_EDGES + e]], 1);
    }
}

// ---- K2: per-block exclusive scan of cnt + block totals to aux
__global__ void scanA_kernel(int* __restrict__ cnt, int* __restrict__ aux) {
    __shared__ int buf[256];
    int t = threadIdx.x, i = blockIdx.x * 256 + t;
    int v = (i < N_NODES) ? cnt[i] : 0;
    buf[t] = v;
    __syncthreads();
    for (int off = 1; off < 256; off <<= 1) {
        int u = (t >= off) ? buf[t - off] : 0;
        __syncthreads();
        buf[t] += u;
        __syncthreads();
    }
    if (i < N_NODES) cnt[i] = buf[t] - v;         // exclusive within block
    if (t == 255) aux[blockIdx.x] = buf[255];     // block total
}

// ---- K3: scatter (blocks 0..3124, scans aux locally) + lin1 (blocks 3125..3906)
__global__ __launch_bounds__(256, 2) void scatter_lin1_kernel(
        const int* __restrict__ eidx, int* __restrict__ cursor, const int* __restrict__ aux,
        int2* __restrict__ spair,
        const float* __restrict__ x, const unsigned short* __restrict__ W1t,
        const float* __restrict__ b1, unsigned short* __restrict__ hbf) {
    __shared__ __align__(16) unsigned short w1t[128 * 136];   // lin1 path; head reused as scan buf
    int tid = threadIdx.x;
    int bid = blockIdx.x;
    if (bid < HIST_B) {
        // local exclusive scan of aux[196]
        int* buf = (int*)w1t;
        int v = (tid < SCAN_B) ? aux[tid] : 0;
        buf[tid] = v;
        __syncthreads();
        for (int off = 1; off < 256; off <<= 1) {
            int u = (tid >= off) ? buf[tid - off] : 0;
            __syncthreads();
            buf[tid] += u;
            __syncthreads();
        }
        int excl = buf[tid] - v;
        __syncthreads();
        buf[tid] = excl;
        __syncthreads();
        int e = bid * 256 + tid;                  // exactly covers 800000
        int d = eidx[N_EDGES + e];
        int p = atomicAdd(&cursor[d], 1) + buf[d >> 8];
        spair[p] = make_int2(eidx[e], d);
        return;
    }
    // ---- lin1 path
    int bl = bid - HIST_B;
    #pragma unroll
    for (int it = 0; it < 8; it++) {
        int idx = (tid + it * 256) * 8;           // element offset, 8 shorts / 16B
        int n = idx >> 7, k = idx & 127;
        *(u32x4*)(&w1t[n * 136 + k]) = *(const u32x4*)(&W1t[idx]);
    }
    __syncthreads();
    int w = tid >> 6, lane = tid & 63;
    int lr = lane & 15, q = lane >> 4;
    int row0 = bl * 64 + w * 16;
    int rowA = row0 + lr; if (rowA >= N_NODES) rowA = N_NODES - 1;
    f32x4 acc[8];
    #pragma unroll
    for (int ct = 0; ct < 8; ct++) acc[ct] = (f32x4){0.f, 0.f, 0.f, 0.f};
    #pragma unroll
    for (int kt = 0; kt < 4; kt++) {
        const float* ap = x + (size_t)rowA * DIM + kt * 32 + q * 8;
        f32x4 x0 = *(const f32x4*)(ap);
        f32x4 x1 = *(const f32x4*)(ap + 4);
        bf16x8 a;
        #pragma unroll
        for (int j = 0; j < 4; j++) { a[j] = (__bf16)x0[j]; a[j + 4] = (__bf16)x1[j]; }
        #pragma unroll
        for (int ct = 0; ct < 8; ct++) {
            bf16x8 b = __builtin_bit_cast(bf16x8,
                *(const u32x4*)(&w1t[(ct * 16 + lr) * 136 + kt * 32 + q * 8]));
            acc[ct] = __builtin_amdgcn_mfma_f32_16x16x32_bf16(a, b, acc[ct], 0, 0, 0);
        }
    }
    #pragma unroll
    for (int ct = 0; ct < 8; ct++) {
        int col = ct * 16 + lr;
        float bias = b1[col];
        #pragma unroll
        for (int r = 0; r < 4; r++) {
            int row = row0 + q * 4 + r;   // C/D: col=lane&15, row=quad*4+reg
            if (row < N_NODES)
                hbf[(size_t)row * DIM + col] = f2bf(acc[ct][r] + bias);
        }
    }
}

// ---- K4: fused edge MLP + segmented scatter-max over dst-sorted edges
__global__ __launch_bounds__(256, 3) void edge_kernel(
        const unsigned short* __restrict__ hbf,
        const int2* __restrict__ spair,
        const unsigned short* __restrict__ Wat,
        const unsigned short* __restrict__ Wbt,
        const unsigned short* __restrict__ W3t,
        const float* __restrict__ b2,
        const float* __restrict__ b3,
        unsigned int* __restrict__ out) {
    __shared__ __align__(16) unsigned short gbuf[2 * 64 * 136];  // hi|hj; reused as fp32 m2 [64][132]
    __shared__ __align__(16) unsigned short m1_lds[64 * 136];
    __shared__ int s_dst[64];

    unsigned short* hi_lds = gbuf;
    unsigned short* hj_lds = gbuf + 64 * 136;
    float* m2f = (float*)gbuf;

    int tid = threadIdx.x;
    int w = tid >> 6, lane = tid & 63;
    int lr = lane & 15, q = lane >> 4;
    int tr = tid >> 4;             // tile-row group 0..15
    int c = (tid & 15) * 8;        // col chunk (shorts)

    // register-cached B fragments (fixed cols per wave, amortized over grid-stride loop)
    bf16x8 baf[2][4], bbf[2][4], b3f[2][4];
    float b2v[2], b3v[2];
    #pragma unroll
    for (int ct = 0; ct < 2; ct++) {
        int n = (2 * w + ct) * 16 + lr;
        #pragma unroll
        for (int kt = 0; kt < 4; kt++) {
            baf[ct][kt] = __builtin_bit_cast(bf16x8, *(const u32x4*)(&Wat[n * 128 + kt * 32 + q * 8]));
            bbf[ct][kt] = __builtin_bit_cast(bf16x8, *(const u32x4*)(&Wbt[n * 128 + kt * 32 + q * 8]));
            b3f[ct][kt] = __builtin_bit_cast(bf16x8, *(const u32x4*)(&W3t[n * 128 + kt * 32 + q * 8]));
        }
        b2v[ct] = b2[n];
        b3v[ct] = b3[n];
    }

    int tb = blockIdx.x;
    int2 pr[4];
    {
        int eb = tb * 64;
        #pragma unroll
        for (int it = 0; it < 4; it++) pr[it] = spair[eb + tr + 16 * it];
    }

    for (; tb < NTILES; tb += gridDim.x) {
        // gather this tile (indices already resident in pr) straight to LDS
        #pragma unroll
        for (int it = 0; it < 4; it++) {
            int t = tr + 16 * it;
            u32x4 gi = *(const u32x4*)(&hbf[(size_t)pr[it].y * DIM + c]);
            u32x4 gj = *(const u32x4*)(&hbf[(size_t)pr[it].x * DIM + c]);
            *(u32x4*)(&hi_lds[t * 136 + c]) = gi;
            *(u32x4*)(&hj_lds[t * 136 + c]) = gj;
        }
        if ((tid & 15) == 0) {
            #pragma unroll
            for (int it = 0; it < 4; it++) s_dst[tr + 16 * it] = pr[it].y;
        }
        __syncthreads();

        // prefetch next tile's indices (drains in the m1 barrier's slack, not on gather path)
        int nx = tb + (int)gridDim.x;
        int2 npr[4];
        if (nx < NTILES) {
            int eb = nx * 64;
            #pragma unroll
            for (int it = 0; it < 4; it++) npr[it] = spair[eb + tr + 16 * it];
        }

        // GEMM1: m1 = relu(h_i@Wa + h_j@Wb + b2)
        f32x4 acc1[4][2];
        #pragma unroll
        for (int rt = 0; rt < 4; rt++)
            #pragma unroll
            for (int ct = 0; ct < 2; ct++) acc1[rt][ct] = (f32x4){0.f, 0.f, 0.f, 0.f};
        #pragma unroll
        for (int kt = 0; kt < 4; kt++) {
            #pragma unroll
            for (int rt = 0; rt < 4; rt++) {
                bf16x8 ai = __builtin_bit_cast(bf16x8,
                    *(const u32x4*)(&hi_lds[(rt * 16 + lr) * 136 + kt * 32 + q * 8]));
                bf16x8 aj = __builtin_bit_cast(bf16x8,
                    *(const u32x4*)(&hj_lds[(rt * 16 + lr) * 136 + kt * 32 + q * 8]));
                acc1[rt][0] = __builtin_amdgcn_mfma_f32_16x16x32_bf16(ai, baf[0][kt], acc1[rt][0], 0, 0, 0);
                acc1[rt][1] = __builtin_amdgcn_mfma_f32_16x16x32_bf16(ai, baf[1][kt], acc1[rt][1], 0, 0, 0);
                acc1[rt][0] = __builtin_amdgcn_mfma_f32_16x16x32_bf16(aj, bbf[0][kt], acc1[rt][0], 0, 0, 0);
                acc1[rt][1] = __builtin_amdgcn_mfma_f32_16x16x32_bf16(aj, bbf[1][kt], acc1[rt][1], 0, 0, 0);
            }
        }
        #pragma unroll
        for (int rt = 0; rt < 4; rt++) {
            #pragma unroll
            for (int ct = 0; ct < 2; ct++) {
                int col = (2 * w + ct) * 16 + lr;
                #pragma unroll
                for (int r = 0; r < 4; r++) {
                    float v = fmaxf(acc1[rt][ct][r] + b2v[ct], 0.f);
                    m1_lds[(rt * 16 + q * 4 + r) * 136 + col] = f2bf(v);
                }
            }
        }
        __syncthreads();   // m1 ready; GEMM1 reads of gbuf done -> m2f reuse safe

        // GEMM2: m2 = relu(m1 @ W3 + b3)
        f32x4 acc2[4][2];
        #pragma unroll
        for (int rt = 0; rt < 4; rt++)
            #pragma unroll
            for (int ct = 0; ct < 2; ct++) acc2[rt][ct] = (f32x4){0.f, 0.f, 0.f, 0.f};
        #pragma unroll
        for (int kt = 0; kt < 4; kt++) {
            #pragma unroll
            for (int rt = 0; rt < 4; rt++) {
                bf16x8 a = __builtin_bit_cast(bf16x8,
                    *(const u32x4*)(&m1_lds[(rt * 16 + lr) * 136 + kt * 32 + q * 8]));
                acc2[rt][0] = __builtin_amdgcn_mfma_f32_16x16x32_bf16(a, b3f[0][kt], acc2[rt][0], 0, 0, 0);
                acc2[rt][1] = __builtin_amdgcn_mfma_f32_16x16x32_bf16(a, b3f[1][kt], acc2[rt][1], 0, 0, 0);
            }
        }
        #pragma unroll
        for (int rt = 0; rt < 4; rt++) {
            #pragma unroll
            for (int ct = 0; ct < 2; ct++) {
                int col = (2 * w + ct) * 16 + lr;
                #pragma unroll
                for (int r = 0; r < 4; r++) {
                    float v = fmaxf(acc2[rt][ct][r] + b3v[ct], 0.f);
                    m2f[(rt * 16 + q * 4 + r) * 132 + col] = v;
                }
            }
        }
        __syncthreads();

        // segmented max over sorted dst runs: thread -> (col = tid&127, rows r0..r0+31)
        {
            int col = tid & 127;
            int r0 = (tid >> 7) * 32;
            float cur = m2f[r0 * 132 + col];
            int d = s_dst[r0];                          // wave-uniform
            #pragma unroll 4
            for (int i = 1; i < 32; i++) {
                int dn = s_dst[r0 + i];                 // wave-uniform
                float v = m2f[(r0 + i) * 132 + col];
                if (dn != d) {                          // wave-uniform branch
                    atomicMax(&out[(size_t)d * DIM + col], __float_as_uint(cur));
                    d = dn; cur = v;
                } else {
                    cur = fmaxf(cur, v);
                }
            }
            atomicMax(&out[(size_t)d * DIM + col], __float_as_uint(cur));
        }
        __syncthreads();   // protect s_dst/gbuf/m1_lds before next tile's gather commit

        #pragma unroll
        for (int it = 0; it < 4; it++) pr[it] = npr[it];
    }
}

extern "C" void kernel_launch(void* const* d_in, const int* in_sizes, int n_in,
                              void* d_out, int out_size, void* d_ws, size_t ws_size,
                              hipStream_t stream) {
    const float* x  = (const float*)d_in[0];
    const int* eidx = (const int*)d_in[1];
    const float* W1 = (const float*)d_in[2];
    const float* b1 = (const float*)d_in[3];
    const float* W2 = (const float*)d_in[4];
    const float* b2 = (const float*)d_in[5];
    const float* W3 = (const float*)d_in[6];
    const float* b3 = (const float*)d_in[7];

    char* ws = (char*)d_ws;
    unsigned short* hbf = (unsigned short*)ws;                     // 12,800,000 B
    unsigned short* W1t = (unsigned short*)(ws + 12800000);        // 32,768 B
    unsigned short* Wat = (unsigned short*)(ws + 12832768);        // 32,768 B
    unsigned short* Wbt = (unsigned short*)(ws + 12865536);        // 32,768 B
    unsigned short* W3t = (unsigned short*)(ws + 12898304);        // 32,768 B
    int* cnt            = (int*)(ws + 12931072);                   // 200,000 B
    int* aux            = (int*)(ws + 13131072);                   // 1,024 B
    int2* spair         = (int2*)(ws + 13132096);                  // 6,400,000 B -> 19,532,096 total

    hipMemsetAsync(d_out, 0, (size_t)N_NODES * DIM * sizeof(float), stream);
    hipMemsetAsync(cnt, 0, N_NODES * sizeof(int), stream);
    prep_kernel<<<256 + HIST_B, 256, 0, stream>>>(W1, W2, W3, eidx, W1t, Wat, Wbt, W3t, cnt);
    scanA_kernel<<<SCAN_B, 256, 0, stream>>>(cnt, aux);
    scatter_lin1_kernel<<<HIST_B + LIN1_B, 256, 0, stream>>>(eidx, cnt, aux, spair, x, W1t, b1, hbf);
    edge_kernel<<<2048, 256, 0, stream>>>(hbf, spair, Wat, Wbt, W3t, b2, b3, (unsigned int*)d_out);
}